// Round 15
// baseline (697.531 us; speedup 1.0000x reference)
//
#include <hip/hip_runtime.h>
#include <hip/hip_bf16.h>
#include <math.h>

#define T_STEPS 100
#define B 256
#define Q 2048
#define H 1024
#define NIN 4096

typedef __attribute__((ext_vector_type(8))) short bf16x8;
typedef __attribute__((ext_vector_type(4))) short bf16x4;
typedef __attribute__((ext_vector_type(4))) float f32x4;
typedef __attribute__((ext_vector_type(4))) unsigned u32x4;
typedef unsigned long long u64;

/* LDS layout (bytes): two cohorts fully resident */
#define HLDS_A0 0
#define HLDS_A1 16384
#define HLDS_B0 32768
#define HLDS_B1 49152
#define HOUT_A  65536
#define HOUT_B  67584
#define LOGIT_A 69632
#define LOGIT_B 69888
#define SMEM_BYTES 70144

/* workspace layout (bytes) */
#define H0_OFF 0
#define H1_OFF (512 * 1024)
#define LP_OFF (1024 * 1024)             /* lp[100][16 rg][256 s] f32 = 1.6 MB */
#define FLAG_OFF (LP_OFF + 1638400)      /* 8 sgps x 64 B; 16 byte-flags each  */

#define AGENT __HIP_MEMORY_SCOPE_AGENT

__device__ inline unsigned short f2bf(float f) {
    union { float f; unsigned int u; } c; c.f = f;
    unsigned int u = c.u + 0x7fffu + ((c.u >> 16) & 1u);
    return (unsigned short)(u >> 16);
}

/* all 4 bytes of w >= f  (f <= 101, monotonic) */
__device__ __forceinline__ unsigned bytes_ge(unsigned w, unsigned f) {
    return ((w & 0xffu) >= f) & (((w >> 8) & 0xffu) >= f) &
           (((w >> 16) & 0xffu) >= f) & (((w >> 24) & 0xffu) >= f);
}

/* r13-proven barrier: 16 byte-flags in one 16B line, one byte per rg block.
   arrive = vmcnt(0) drain (all waves; drains agent-atomic h/lp stores too)
            + block-sync + tid0 byte-store.
   wait   = tid0 polls the line with one dwordx4; trailing sync releases. */
__device__ __forceinline__ void sgp_bar(unsigned char* fb, int rg, unsigned fval) {
    asm volatile("s_waitcnt vmcnt(0)" ::: "memory");
    __syncthreads();
    if (threadIdx.x == 0) {
        asm volatile("global_store_byte %0, %1, off sc0 sc1"
                     :: "v"(fb + rg), "v"(fval) : "memory");
        u32x4 fw;
        unsigned done;
        do {
            asm volatile("global_load_dwordx4 %0, %1, off sc0 sc1"
                         : "=v"(fw) : "v"(fb));
            asm volatile("s_waitcnt vmcnt(0)" ::: "memory");
            done = bytes_ge(fw[0], fval) & bytes_ge(fw[1], fval) &
                   bytes_ge(fw[2], fval) & bytes_ge(fw[3], fval);
        } while (!done);
    }
    __syncthreads();
}

__global__ void ws_init(unsigned* __restrict__ flags) {
    int idx = blockIdx.x * blockDim.x + threadIdx.x;
    if (idx < 128) flags[idx] = 0u;   /* 8 sgps x 64 B */
}

__global__ __launch_bounds__(256, 1) void rnn_persistent(
    const int* __restrict__ x_idx, const int* __restrict__ y_idx,
    const float* __restrict__ truth,
    const float* __restrict__ Wm, const float* __restrict__ bm,
    const float* __restrict__ Wx, const float* __restrict__ bx_,
    const float* __restrict__ Wy, const float* __restrict__ by,
    const float* __restrict__ b_start,
    __hip_bfloat16* __restrict__ h0buf, __hip_bfloat16* __restrict__ h1buf,
    float* __restrict__ lp, unsigned* __restrict__ flags,
    float* __restrict__ out)
{
    extern __shared__ char lds[];

    const int tid = threadIdx.x;
    const int bid = blockIdx.x;
    const int rg  = bid & 15;         /* row group: rows [rg*64, +64)       */
    const int sgp = bid >> 4;         /* super-group: students [sgp*32,+32) */
    const int sbase = sgp * 32;
    const int w  = tid >> 6;
    const int l  = tid & 63;
    const int lr = l & 15;
    const int g  = l >> 4;

    unsigned char* fb = (unsigned char*)flags + sgp * 64;

    /* ---- one-time setup ---- */
    bf16x8 a_frag[32];
    {
        const int row = rg * 64 + w * 16 + lr;
        const float* wrow = &Wm[(size_t)row * H];
        #pragma unroll
        for (int half = 0; half < 2; ++half) {
            #pragma unroll
            for (int kk = 0; kk < 16; ++kk) {
                int k0 = (half * 64 + kk * 4 + g) * 8;
                float4 v0 = *reinterpret_cast<const float4*>(&wrow[k0]);
                float4 v1 = *reinterpret_cast<const float4*>(&wrow[k0 + 4]);
                bf16x8 f;
                f[0] = (short)f2bf(v0.x); f[1] = (short)f2bf(v0.y);
                f[2] = (short)f2bf(v0.z); f[3] = (short)f2bf(v0.w);
                f[4] = (short)f2bf(v1.x); f[5] = (short)f2bf(v1.y);
                f[6] = (short)f2bf(v1.z); f[7] = (short)f2bf(v1.w);
                a_frag[half * 16 + kk] = f;
            }
        }
    }
    /* h0 = b_start broadcast for 32 students (zeros @ W_start.T == 0) */
    {
        int s = tid >> 3, c = tid & 7;
        union { unsigned short s4[4]; u64 u; } pk0, pk1;
        #pragma unroll
        for (int e = 0; e < 4; ++e) {
            pk0.s4[e] = f2bf(b_start[rg * 64 + c * 8 + e]);
            pk1.s4[e] = f2bf(b_start[rg * 64 + c * 8 + 4 + e]);
        }
        u64* dst = (u64*)&h0buf[(size_t)(sbase + s) * H + rg * 64 + c * 8];
        __hip_atomic_store(dst,     pk0.u, __ATOMIC_RELAXED, AGENT);
        __hip_atomic_store(dst + 1, pk1.u, __ATOMIC_RELAXED, AGENT);
    }
    float bias_r[4];
    #pragma unroll
    for (int r = 0; r < 4; ++r) {
        int gi = rg * 64 + w * 16 + g * 4 + r;
        bias_r[r] = bm[gi] + bx_[gi];
    }
    float wxA[4], wyA[4], wxB[4], wyB[4];
    {
        int xcA = x_idx[sbase + lr],      ycA = y_idx[sbase + lr];
        int xcB = x_idx[sbase + 16 + lr], ycB = y_idx[sbase + 16 + lr];
        #pragma unroll
        for (int r = 0; r < 4; ++r) {
            int gi = rg * 64 + w * 16 + g * 4 + r;
            wxA[r] = Wx[(size_t)gi * NIN + xcA];
            wyA[r] = Wy[(size_t)ycA * H + gi];
            wxB[r] = Wx[(size_t)gi * NIN + xcB];
            wyB[r] = Wy[(size_t)ycB * H + gi];
        }
    }

    sgp_bar(fb, rg, 1u);

    /* ---- recurrence: 2 cohorts per block, one barrier per step ---- */
    for (int t = 0; t < T_STEPS; ++t) {
        const __hip_bfloat16* hc = (t & 1) ? h1buf : h0buf;
        __hip_bfloat16*       hn = (t & 1) ? h0buf : h1buf;

        /* prefetch all h (A/B x half0/half1) via 8B agent atomic loads */
        u64 rA[16], rB[16];
        #pragma unroll
        for (int it = 0; it < 4; ++it) {
            int q = it * 256 + tid;
            int srow = q >> 6, sl = q & 63;
            const u64* sA0 = (const u64*)&hc[(size_t)(sbase + srow) * H + sl * 8];
            const u64* sA1 = (const u64*)&hc[(size_t)(sbase + srow) * H + 512 + sl * 8];
            const u64* sB0 = (const u64*)&hc[(size_t)(sbase + 16 + srow) * H + sl * 8];
            const u64* sB1 = (const u64*)&hc[(size_t)(sbase + 16 + srow) * H + 512 + sl * 8];
            rA[2 * it]         = __hip_atomic_load(sA0,     __ATOMIC_RELAXED, AGENT);
            rA[2 * it + 1]     = __hip_atomic_load(sA0 + 1, __ATOMIC_RELAXED, AGENT);
            rA[8 + 2 * it]     = __hip_atomic_load(sA1,     __ATOMIC_RELAXED, AGENT);
            rA[8 + 2 * it + 1] = __hip_atomic_load(sA1 + 1, __ATOMIC_RELAXED, AGENT);
            rB[2 * it]         = __hip_atomic_load(sB0,     __ATOMIC_RELAXED, AGENT);
            rB[2 * it + 1]     = __hip_atomic_load(sB0 + 1, __ATOMIC_RELAXED, AGENT);
            rB[8 + 2 * it]     = __hip_atomic_load(sB1,     __ATOMIC_RELAXED, AGENT);
            rB[8 + 2 * it + 1] = __hip_atomic_load(sB1 + 1, __ATOMIC_RELAXED, AGENT);
        }

        /* stage both cohorts, single sync */
        #pragma unroll
        for (int it = 0; it < 4; ++it) {
            int q = it * 256 + tid;
            int srow = q >> 6, sl = q & 63;
            int so = srow * 1024 + ((sl ^ (srow & 7)) << 4);
            union { u64 u[2]; bf16x8 v; } cA0, cA1, cB0, cB1;
            cA0.u[0] = rA[2 * it];     cA0.u[1] = rA[2 * it + 1];
            cA1.u[0] = rA[8 + 2 * it]; cA1.u[1] = rA[8 + 2 * it + 1];
            cB0.u[0] = rB[2 * it];     cB0.u[1] = rB[2 * it + 1];
            cB1.u[0] = rB[8 + 2 * it]; cB1.u[1] = rB[8 + 2 * it + 1];
            *reinterpret_cast<bf16x8*>(&lds[HLDS_A0 + so]) = cA0.v;
            *reinterpret_cast<bf16x8*>(&lds[HLDS_A1 + so]) = cA1.v;
            *reinterpret_cast<bf16x8*>(&lds[HLDS_B0 + so]) = cB0.v;
            *reinterpret_cast<bf16x8*>(&lds[HLDS_B1 + so]) = cB1.v;
        }
        __syncthreads();

        /* cohort A: 32 MFMAs, two acc chains */
        f32x4 aA0 = {0.f,0.f,0.f,0.f}, aA1 = {0.f,0.f,0.f,0.f};
        #pragma unroll
        for (int kk = 0; kk < 16; kk += 2) {
            bf16x8 b0 = *reinterpret_cast<const bf16x8*>(
                &lds[HLDS_A0 + lr * 1024 + ((((kk    ) * 4 + g) ^ (lr & 7)) << 4)]);
            aA0 = __builtin_amdgcn_mfma_f32_16x16x32_bf16(a_frag[kk],     b0, aA0, 0, 0, 0);
            bf16x8 b1 = *reinterpret_cast<const bf16x8*>(
                &lds[HLDS_A0 + lr * 1024 + ((((kk + 1) * 4 + g) ^ (lr & 7)) << 4)]);
            aA1 = __builtin_amdgcn_mfma_f32_16x16x32_bf16(a_frag[kk + 1], b1, aA1, 0, 0, 0);
        }
        #pragma unroll
        for (int kk = 0; kk < 16; kk += 2) {
            bf16x8 b0 = *reinterpret_cast<const bf16x8*>(
                &lds[HLDS_A1 + lr * 1024 + ((((kk    ) * 4 + g) ^ (lr & 7)) << 4)]);
            aA0 = __builtin_amdgcn_mfma_f32_16x16x32_bf16(a_frag[16 + kk],     b0, aA0, 0, 0, 0);
            bf16x8 b1 = *reinterpret_cast<const bf16x8*>(
                &lds[HLDS_A1 + lr * 1024 + ((((kk + 1) * 4 + g) ^ (lr & 7)) << 4)]);
            aA1 = __builtin_amdgcn_mfma_f32_16x16x32_bf16(a_frag[16 + kk + 1], b1, aA1, 0, 0, 0);
        }
        /* cohort B: 32 MFMAs */
        f32x4 aB0 = {0.f,0.f,0.f,0.f}, aB1 = {0.f,0.f,0.f,0.f};
        #pragma unroll
        for (int kk = 0; kk < 16; kk += 2) {
            bf16x8 b0 = *reinterpret_cast<const bf16x8*>(
                &lds[HLDS_B0 + lr * 1024 + ((((kk    ) * 4 + g) ^ (lr & 7)) << 4)]);
            aB0 = __builtin_amdgcn_mfma_f32_16x16x32_bf16(a_frag[kk],     b0, aB0, 0, 0, 0);
            bf16x8 b1 = *reinterpret_cast<const bf16x8*>(
                &lds[HLDS_B0 + lr * 1024 + ((((kk + 1) * 4 + g) ^ (lr & 7)) << 4)]);
            aB1 = __builtin_amdgcn_mfma_f32_16x16x32_bf16(a_frag[kk + 1], b1, aB1, 0, 0, 0);
        }
        #pragma unroll
        for (int kk = 0; kk < 16; kk += 2) {
            bf16x8 b0 = *reinterpret_cast<const bf16x8*>(
                &lds[HLDS_B1 + lr * 1024 + ((((kk    ) * 4 + g) ^ (lr & 7)) << 4)]);
            aB0 = __builtin_amdgcn_mfma_f32_16x16x32_bf16(a_frag[16 + kk],     b0, aB0, 0, 0, 0);
            bf16x8 b1 = *reinterpret_cast<const bf16x8*>(
                &lds[HLDS_B1 + lr * 1024 + ((((kk + 1) * 4 + g) ^ (lr & 7)) << 4)]);
            aB1 = __builtin_amdgcn_mfma_f32_16x16x32_bf16(a_frag[16 + kk + 1], b1, aB1, 0, 0, 0);
        }

        /* epilogues */
        {
            float hvo[4];
            #pragma unroll
            for (int r = 0; r < 4; ++r)
                hvo[r] = tanhf(aA0[r] + aA1[r] + bias_r[r] + wxA[r]);
            int row0 = w * 16 + g * 4, chunk = row0 >> 3;
            bf16x4 b4;
            b4[0] = (short)f2bf(hvo[0]); b4[1] = (short)f2bf(hvo[1]);
            b4[2] = (short)f2bf(hvo[2]); b4[3] = (short)f2bf(hvo[3]);
            *reinterpret_cast<bf16x4*>(
                &lds[HOUT_A + lr * 128 + ((chunk ^ (lr & 7)) << 4) + ((row0 & 7) << 1)]) = b4;
            float p = hvo[0] * wyA[0] + hvo[1] * wyA[1] + hvo[2] * wyA[2] + hvo[3] * wyA[3];
            p += __shfl_down(p, 32);
            p += __shfl_down(p, 16);
            if (l < 16)
                *reinterpret_cast<float*>(&lds[LOGIT_A + (w * 16 + l) * 4]) = p;
        }
        {
            float hvo[4];
            #pragma unroll
            for (int r = 0; r < 4; ++r)
                hvo[r] = tanhf(aB0[r] + aB1[r] + bias_r[r] + wxB[r]);
            int row0 = w * 16 + g * 4, chunk = row0 >> 3;
            bf16x4 b4;
            b4[0] = (short)f2bf(hvo[0]); b4[1] = (short)f2bf(hvo[1]);
            b4[2] = (short)f2bf(hvo[2]); b4[3] = (short)f2bf(hvo[3]);
            *reinterpret_cast<bf16x4*>(
                &lds[HOUT_B + lr * 128 + ((chunk ^ (lr & 7)) << 4) + ((row0 & 7) << 1)]) = b4;
            float p = hvo[0] * wyB[0] + hvo[1] * wyB[1] + hvo[2] * wyB[2] + hvo[3] * wyB[3];
            p += __shfl_down(p, 32);
            p += __shfl_down(p, 16);
            if (l < 16)
                *reinterpret_cast<float*>(&lds[LOGIT_B + (w * 16 + l) * 4]) = p;
        }
        __syncthreads();

        /* h_next write-out: 8B agent atomic stores (r7-proven pattern), both cohorts */
        {
            int s = tid >> 4, c8 = tid & 15;
            int lo = s * 128 + (((c8 >> 1) ^ (s & 7)) << 4) + ((c8 & 1) << 3);
            u64 vA = *reinterpret_cast<const u64*>(&lds[HOUT_A + lo]);
            u64 vB = *reinterpret_cast<const u64*>(&lds[HOUT_B + lo]);
            __hip_atomic_store((u64*)&hn[(size_t)(sbase + s) * H + rg * 64 + c8 * 4],
                               vA, __ATOMIC_RELAXED, AGENT);
            __hip_atomic_store((u64*)&hn[(size_t)(sbase + 16 + s) * H + rg * 64 + c8 * 4],
                               vB, __ATOMIC_RELAXED, AGENT);
        }
        if (tid < 16) {
            const float* lgA = reinterpret_cast<const float*>(&lds[LOGIT_A]);
            const float* lgB = reinterpret_cast<const float*>(&lds[LOGIT_B]);
            float psA = lgA[tid] + lgA[16 + tid] + lgA[32 + tid] + lgA[48 + tid];
            float psB = lgB[tid] + lgB[16 + tid] + lgB[32 + tid] + lgB[48 + tid];
            __hip_atomic_store(&lp[(size_t)(t * 16 + rg) * B + sbase + tid],
                               psA, __ATOMIC_RELAXED, AGENT);
            __hip_atomic_store(&lp[(size_t)(t * 16 + rg) * B + sbase + 16 + tid],
                               psB, __ATOMIC_RELAXED, AGENT);
        }

        /* next-step gathers (loads; drained with the barrier's vmcnt) */
        {
            int tn = (t + 1 < T_STEPS) ? t + 1 : t;
            int xcA = x_idx[tn * B + sbase + lr],      ycA = y_idx[tn * B + sbase + lr];
            int xcB = x_idx[tn * B + sbase + 16 + lr], ycB = y_idx[tn * B + sbase + 16 + lr];
            #pragma unroll
            for (int r = 0; r < 4; ++r) {
                int gi = rg * 64 + w * 16 + g * 4 + r;
                wxA[r] = Wx[(size_t)gi * NIN + xcA];
                wyA[r] = Wy[(size_t)ycA * H + gi];
                wxB[r] = Wx[(size_t)gi * NIN + xcB];
                wyB[r] = Wy[(size_t)ycB * H + gi];
            }
        }

        sgp_bar(fb, rg, (unsigned)(t + 2));
    }

    /* ---- final: block (rg,sgp) handles t = rg, rg+16, ... for its 32 students ---- */
    {
        int ti = tid >> 5, s = tid & 31;
        int t = rg + ti * 16;
        if (t < T_STEPS) {
            int idx = t * B + sbase + s;
            float lgv = 0.f;
            #pragma unroll
            for (int rgi = 0; rgi < 16; ++rgi)
                lgv += __hip_atomic_load(&lp[(size_t)(t * 16 + rgi) * B + sbase + s],
                                         __ATOMIC_RELAXED, AGENT);
            int yc = y_idx[idx];
            lgv += by[yc];
            float pred = 1.f / (1.f + expf(-lgv));
            float tv = truth[idx];
            float e = log1pf(expf(-fabsf(lgv)));
            float ls_pos = fminf(lgv, 0.f) - e;
            float ls_neg = fminf(-lgv, 0.f) - e;
            out[idx] = pred;
            out[T_STEPS * B + idx] = -(tv * ls_pos + (1.f - tv) * ls_neg);
        }
    }
}

extern "C" void kernel_launch(void* const* d_in, const int* in_sizes, int n_in,
                              void* d_out, int out_size, void* d_ws, size_t ws_size,
                              hipStream_t stream) {
    const int*   x_idx   = (const int*)d_in[0];
    const int*   y_idx   = (const int*)d_in[1];
    const float* truth   = (const float*)d_in[2];
    const float* Wm      = (const float*)d_in[3];
    const float* bm      = (const float*)d_in[4];
    const float* Wx      = (const float*)d_in[5];
    const float* bx_     = (const float*)d_in[6];
    const float* Wy      = (const float*)d_in[7];
    const float* by      = (const float*)d_in[8];
    /* d_in[9] = W_start: dead (multiplied by zeros) */
    const float* b_start = (const float*)d_in[10];
    float* out = (float*)d_out;

    __hip_bfloat16* h0buf = (__hip_bfloat16*)((char*)d_ws + H0_OFF);
    __hip_bfloat16* h1buf = (__hip_bfloat16*)((char*)d_ws + H1_OFF);
    float*          lp    = (float*)((char*)d_ws + LP_OFF);
    unsigned*       flags = (unsigned*)((char*)d_ws + FLAG_OFF);

    ws_init<<<1, 256, 0, stream>>>(flags);

    hipFuncSetAttribute(reinterpret_cast<const void*>(rnn_persistent),
                        hipFuncAttributeMaxDynamicSharedMemorySize, SMEM_BYTES);

    /* plain launch: 128 blocks on 256 CUs are unconditionally co-resident. */
    rnn_persistent<<<dim3(128), dim3(256), SMEM_BYTES, stream>>>(
        x_idx, y_idx, truth, Wm, bm, Wx, bx_, Wy, by, b_start,
        h0buf, h1buf, lp, flags, out);
}